// Round 2
// baseline (345.178 us; speedup 1.0000x reference)
//
#include <hip/hip_runtime.h>
#include <stdint.h>

// Problem constants
#define B_BATCH 2048     // batch rows (softmax columns here)
#define D_K     128      // embedding dim = GEMM K
#define N_ENT   100000   // entities = GEMM M (LSE reduction axis)
#define BM      128      // entities per chunk (one block per chunk)
#define NCHUNK  ((N_ENT + BM - 1) / BM)   // 782
#define TB      128      // batch columns per register tile
#define NTILE   (B_BATCH / TB)            // 16

typedef __attribute__((ext_vector_type(8))) __bf16 bf16x8;
typedef __attribute__((ext_vector_type(8))) short  short8;
typedef __attribute__((ext_vector_type(4))) float  f32x4;

__device__ __forceinline__ short f2bf(float x) {
  // RNE fp32 -> bf16
  unsigned int u = __float_as_uint(x);
  unsigned int r = (u + 0x7fffu + ((u >> 16) & 1u)) >> 16;
  return (short)r;
}

__device__ __forceinline__ short8 pack8(f32x4 a, f32x4 b) {
  short8 v;
  v[0] = f2bf(a[0]); v[1] = f2bf(a[1]); v[2] = f2bf(a[2]); v[3] = f2bf(a[3]);
  v[4] = f2bf(b[0]); v[5] = f2bf(b[1]); v[6] = f2bf(b[2]); v[7] = f2bf(b[3]);
  return v;
}

// ---------------------------------------------------------------------------
// Pre-kernel: X fp32 [2048][128] -> bf16 row-major (done once; X then lives
// in L2 as 512 KB and is re-read by every block's B-fragment loads).
// ---------------------------------------------------------------------------
__global__ __launch_bounds__(256)
void convert_x_kernel(const float* __restrict__ X, unsigned short* __restrict__ Xb)
{
  int i = (blockIdx.x * 256 + threadIdx.x) * 8;   // 8 elems/thread, 32768 threads
  f32x4 f0 = *(const f32x4*)(X + i);
  f32x4 f1 = *(const f32x4*)(X + i + 4);
  *(short8*)(Xb + i) = pack8(f0, f1);
}

// ---------------------------------------------------------------------------
// Main kernel: one block per 128-entity chunk. NO LDS, NO barriers.
//  - A-fragments (E rows, fp32->bf16 in reg) loaded once per chunk
//  - 16 batch tiles: B-frags direct from bf16 X (L2), 64 MFMA/wave,
//    epilogue = plain sum-of-exp per column (range analysis: logits < ~80,
//    sum < 1e35 << fp32 max -> no max tracking needed)
//  - per-column partial written straight to P[g][wm][col]; every batch column
//    occurs in exactly one (it,wn,nj) slot per chunk, so no accumulation.
// ---------------------------------------------------------------------------
__global__ __launch_bounds__(256, 2)
void fused_lse_kernel(const unsigned short* __restrict__ Xb,  // [2048][128] bf16
                      const float* __restrict__ E,            // [100000][128] fp32
                      const float* __restrict__ bias,         // [100000]
                      float* __restrict__ P)                  // [NCHUNK][2][2048]
{
  const int g          = blockIdx.x;
  const int ent0       = g * BM;
  const int rows_valid = min(BM, N_ENT - ent0);

  const int t    = threadIdx.x;
  const int lane = t & 63;
  const int w    = t >> 6;
  const int wm   = w & 1;        // wave entity-half (rows 0-63 / 64-127)
  const int wn   = w >> 1;       // wave batch-half (cols 0-63 / 64-127 of tile)
  const int lg   = lane >> 4;    // lane group 0..3 (k-subgroup)
  const int l15  = lane & 15;
  const float LOG2E = 1.4426950408889634f;

  // ---- resident A fragments: rows wm*64 + mi*16 + l15, k = kk*32 + lg*8 ----
  bf16x8 Areg[4][4];
  #pragma unroll
  for (int mi = 0; mi < 4; ++mi) {
    int row = wm * 64 + mi * 16 + l15;
    #pragma unroll
    for (int kk = 0; kk < 4; ++kk) {
      f32x4 f0 = {0.f, 0.f, 0.f, 0.f}, f1 = {0.f, 0.f, 0.f, 0.f};
      if (row < rows_valid) {
        const float* src = E + (size_t)(ent0 + row) * D_K + kk * 32 + lg * 8;
        f0 = *(const f32x4*)src;
        f1 = *(const f32x4*)(src + 4);
      }
      Areg[mi][kk] = __builtin_bit_cast(bf16x8, pack8(f0, f1));
    }
  }

  // per-thread accumulator-row bias*LOG2E; invalid rows -> -1e30 (exp2 -> 0)
  // acc D layout: col = lane&15, row = mi*16 + lg*4 + r   [m89/m91 verified]
  float browl[16];
  #pragma unroll
  for (int mi = 0; mi < 4; ++mi)
    #pragma unroll
    for (int r = 0; r < 4; ++r) {
      int row = wm * 64 + mi * 16 + lg * 4 + r;
      browl[mi * 4 + r] = (row < rows_valid) ? bias[ent0 + row] * LOG2E : -1e30f;
    }

  // ---- 16 batch tiles ----
  for (int it = 0; it < NTILE; ++it) {
    f32x4 acc[4][4];
    #pragma unroll
    for (int mi = 0; mi < 4; ++mi)
      #pragma unroll
      for (int nj = 0; nj < 4; ++nj)
        acc[mi][nj] = (f32x4){0.f, 0.f, 0.f, 0.f};

    #pragma unroll
    for (int kk = 0; kk < 4; ++kk) {
      bf16x8 Breg[4];
      #pragma unroll
      for (int nj = 0; nj < 4; ++nj) {
        int brow = it * TB + wn * 64 + nj * 16 + l15;     // batch row
        Breg[nj] = __builtin_bit_cast(bf16x8,
            *(const short8*)(Xb + (size_t)brow * D_K + kk * 32 + lg * 8));
      }
      #pragma unroll
      for (int mi = 0; mi < 4; ++mi)
        #pragma unroll
        for (int nj = 0; nj < 4; ++nj)
          acc[mi][nj] = __builtin_amdgcn_mfma_f32_16x16x32_bf16(
              Areg[mi][kk], Breg[nj], acc[mi][nj], 0, 0, 0);
    }

    // ---- epilogue: per-column plain sum of exp over this wave's 64 rows ----
    #pragma unroll
    for (int nj = 0; nj < 4; ++nj) {
      float sm[4];
      #pragma unroll
      for (int mi = 0; mi < 4; ++mi) {
        float e0 = exp2f(fmaf(acc[mi][nj][0], LOG2E, browl[mi * 4 + 0]));
        float e1 = exp2f(fmaf(acc[mi][nj][1], LOG2E, browl[mi * 4 + 1]));
        float e2 = exp2f(fmaf(acc[mi][nj][2], LOG2E, browl[mi * 4 + 2]));
        float e3 = exp2f(fmaf(acc[mi][nj][3], LOG2E, browl[mi * 4 + 3]));
        sm[mi] = (e0 + e1) + (e2 + e3);
      }
      float s = (sm[0] + sm[1]) + (sm[2] + sm[3]);
      // lanes {c, c+16, c+32, c+48} hold the same column -> fold lg groups
      s += __shfl_xor(s, 16);
      s += __shfl_xor(s, 32);
      if (lane < 16) {
        int col = it * TB + wn * 64 + nj * 16 + lane;
        P[((size_t)g * 2 + wm) * B_BATCH + col] = s;
      }
    }
  }
}

// ---------------------------------------------------------------------------
// Reduce: per batch col, sum the 2*NCHUNK partials; exact fp32 target logit.
// ---------------------------------------------------------------------------
__global__ __launch_bounds__(256)
void reduce_kernel(const float* __restrict__ P,
                   const float* __restrict__ X, const float* __restrict__ E,
                   const float* __restrict__ bias, const int* __restrict__ y,
                   float* __restrict__ loss)
{
  int t  = threadIdx.x;
  int tx = t >> 2;            // 0..63 -> column
  int ty = t & 3;             // 0..3  -> partial stripe
  int b  = blockIdx.x * 64 + tx;

  float s = 0.f;
  const int NP = 2 * NCHUNK;
  for (int p = ty; p < NP; p += 4)
    s += P[(size_t)p * B_BATCH + b];

  int yb = y[b];
  const f32x4* xr = (const f32x4*)(X + (size_t)b  * D_K);
  const f32x4* er = (const f32x4*)(E + (size_t)yb * D_K);
  float dot = 0.f;
  #pragma unroll
  for (int j = 0; j < 8; ++j) {
    f32x4 a = xr[ty * 8 + j], e = er[ty * 8 + j];
    dot += a[0]*e[0] + a[1]*e[1] + a[2]*e[2] + a[3]*e[3];
  }

  #pragma unroll
  for (int sh = 1; sh <= 2; sh <<= 1) {
    s   += __shfl_xor(s, sh);
    dot += __shfl_xor(dot, sh);
  }
  if (ty == 0)
    loss[b] = 0.6931471805599453f * log2f(s) - (dot + bias[yb]);
}

__global__ __launch_bounds__(256)
void final_kernel(const float* __restrict__ loss, float* __restrict__ out)
{
  __shared__ float wsum[4];
  int t = threadIdx.x;
  float s = 0.f;
  for (int j = t; j < B_BATCH; j += 256) s += loss[j];
  #pragma unroll
  for (int sh = 1; sh <= 32; sh <<= 1) s += __shfl_xor(s, sh);
  if ((t & 63) == 0) wsum[t >> 6] = s;
  __syncthreads();
  if (t == 0) out[0] = (wsum[0] + wsum[1] + wsum[2] + wsum[3]) / (float)B_BATCH;
}

extern "C" void kernel_launch(void* const* d_in, const int* in_sizes, int n_in,
                              void* d_out, int out_size, void* d_ws, size_t ws_size,
                              hipStream_t stream)
{
  (void)in_sizes; (void)n_in; (void)out_size; (void)ws_size;
  const float* X    = (const float*)d_in[0];   // entity_embeddings [2048,128]
  const float* E    = (const float*)d_in[1];   // entity_embs [100000,128]
  const float* bias = (const float*)d_in[2];   // rec_entity_bias [100000]
  const int*   y    = (const int*)d_in[3];     // labels [2048]
  float* out = (float*)d_out;

  // ws layout: P float[NCHUNK*2*2048] (12.8 MB) | Xb bf16[2048*128] (512 KB)
  //            | loss float[2048]
  float*          P    = (float*)d_ws;
  unsigned short* Xb   = (unsigned short*)((char*)d_ws +
                          (size_t)NCHUNK * 2 * B_BATCH * sizeof(float));
  float*          loss = (float*)((char*)Xb + (size_t)B_BATCH * D_K * sizeof(unsigned short));

  convert_x_kernel<<<(B_BATCH * D_K / 8) / 256, 256, 0, stream>>>(X, Xb);
  fused_lse_kernel<<<NCHUNK, 256, 0, stream>>>(Xb, E, bias, P);
  reduce_kernel<<<B_BATCH / 64, 256, 0, stream>>>(P, X, E, bias, y, loss);
  final_kernel<<<1, 256, 0, stream>>>(loss, out);
}

// Round 3
// 307.774 us; speedup vs baseline: 1.1215x; 1.1215x over previous
//
#include <hip/hip_runtime.h>
#include <stdint.h>

// Problem constants
#define B_BATCH 2048     // batch rows (softmax columns here)
#define D_K     128      // embedding dim = GEMM K
#define N_ENT   100000   // entities = GEMM M (LSE reduction axis)
#define BM      128      // entities per chunk
#define NCHUNK  ((N_ENT + BM - 1) / BM)   // 782
#define TB      128      // batch columns per register tile
#define NBH     2        // batch halves (grid split)
#define BHCOLS  (B_BATCH / NBH)           // 1024
#define NTILE   (BHCOLS / TB)             // 8

typedef __attribute__((ext_vector_type(8))) __bf16 bf16x8;
typedef __attribute__((ext_vector_type(8))) short  short8;
typedef __attribute__((ext_vector_type(4))) float  f32x4;

__device__ __forceinline__ short f2bf(float x) {
  // RNE fp32 -> bf16
  unsigned int u = __float_as_uint(x);
  unsigned int r = (u + 0x7fffu + ((u >> 16) & 1u)) >> 16;
  return (short)r;
}

__device__ __forceinline__ short8 pack8(f32x4 a, f32x4 b) {
  short8 v;
  v[0] = f2bf(a[0]); v[1] = f2bf(a[1]); v[2] = f2bf(a[2]); v[3] = f2bf(a[3]);
  v[4] = f2bf(b[0]); v[5] = f2bf(b[1]); v[6] = f2bf(b[2]); v[7] = f2bf(b[3]);
  return v;
}

// ---------------------------------------------------------------------------
// Pre-kernel: X fp32 -> bf16 (once; 512 KB, L2/L3-resident afterwards).
// Also zeroes the atomic accumulator S[2048] (d_ws is poisoned every launch).
// ---------------------------------------------------------------------------
__global__ __launch_bounds__(256)
void convert_x_kernel(const float* __restrict__ X, unsigned short* __restrict__ Xb,
                      float* __restrict__ S)
{
  int gid = blockIdx.x * 256 + threadIdx.x;
  int i = gid * 8;
  f32x4 f0 = *(const f32x4*)(X + i);
  f32x4 f1 = *(const f32x4*)(X + i + 4);
  *(short8*)(Xb + i) = pack8(f0, f1);
  if (gid < B_BATCH) S[gid] = 0.f;
}

// ---------------------------------------------------------------------------
// Main kernel: grid = NCHUNK x NBH. Block (g, bh) computes the 128-entity
// chunk g against batch half bh (1024 cols). NO LDS, NO barriers.
//  - A-fragments (E rows, fp32->bf16 in reg) loaded once per block
//  - 8 batch tiles: B-frags direct from bf16 X (L2), 64 MFMA/wave,
//    epilogue = plain sum-of-exp per column (range analysis: logits < ~80,
//    sum < 1e35 << fp32 max -> no max tracking needed)
//  - per-column partial atomicAdd'ed into S[col] (fp32; ~1.5K adds/addr
//    spread over the kernel -> negligible contention; reorder error ~1e-6 rel)
// ---------------------------------------------------------------------------
__global__ __launch_bounds__(256, 2)
void fused_lse_kernel(const unsigned short* __restrict__ Xb,  // [2048][128] bf16
                      const float* __restrict__ E,            // [100000][128] fp32
                      const float* __restrict__ bias,         // [100000]
                      float* __restrict__ S)                  // [2048] atomic sums
{
  const int g    = blockIdx.x >> 1;       // entity chunk
  const int bh   = blockIdx.x & 1;        // batch half
  const int ent0 = g * BM;
  const int rows_valid = min(BM, N_ENT - ent0);

  const int t    = threadIdx.x;
  const int lane = t & 63;
  const int w    = t >> 6;
  const int wm   = w & 1;        // wave entity-half (rows 0-63 / 64-127)
  const int wn   = w >> 1;       // wave batch-half within tile
  const int lg   = lane >> 4;    // lane group 0..3 (k-subgroup)
  const int l15  = lane & 15;
  const float LOG2E = 1.4426950408889634f;

  // ---- resident A fragments: rows wm*64 + mi*16 + l15, k = kk*32 + lg*8 ----
  bf16x8 Areg[4][4];
  #pragma unroll
  for (int mi = 0; mi < 4; ++mi) {
    int row = wm * 64 + mi * 16 + l15;
    #pragma unroll
    for (int kk = 0; kk < 4; ++kk) {
      f32x4 f0 = {0.f, 0.f, 0.f, 0.f}, f1 = {0.f, 0.f, 0.f, 0.f};
      if (row < rows_valid) {
        const float* src = E + (size_t)(ent0 + row) * D_K + kk * 32 + lg * 8;
        f0 = *(const f32x4*)src;
        f1 = *(const f32x4*)(src + 4);
      }
      Areg[mi][kk] = __builtin_bit_cast(bf16x8, pack8(f0, f1));
    }
  }

  // per-thread accumulator-row bias*LOG2E; invalid rows -> -1e30 (exp2 -> 0)
  // acc D layout: col = lane&15, row = mi*16 + lg*4 + r   [m89/m91 verified]
  float browl[16];
  #pragma unroll
  for (int mi = 0; mi < 4; ++mi)
    #pragma unroll
    for (int r = 0; r < 4; ++r) {
      int row = wm * 64 + mi * 16 + lg * 4 + r;
      browl[mi * 4 + r] = (row < rows_valid) ? bias[ent0 + row] * LOG2E : -1e30f;
    }

  // ---- 8 batch tiles of this half ----
  for (int it = 0; it < NTILE; ++it) {
    const int colbase = bh * BHCOLS + it * TB;

    f32x4 acc[4][4];
    #pragma unroll
    for (int mi = 0; mi < 4; ++mi)
      #pragma unroll
      for (int nj = 0; nj < 4; ++nj)
        acc[mi][nj] = (f32x4){0.f, 0.f, 0.f, 0.f};

    #pragma unroll
    for (int kk = 0; kk < 4; ++kk) {
      bf16x8 Breg[4];
      #pragma unroll
      for (int nj = 0; nj < 4; ++nj) {
        int brow = colbase + wn * 64 + nj * 16 + l15;     // batch row
        Breg[nj] = __builtin_bit_cast(bf16x8,
            *(const short8*)(Xb + (size_t)brow * D_K + kk * 32 + lg * 8));
      }
      #pragma unroll
      for (int mi = 0; mi < 4; ++mi)
        #pragma unroll
        for (int nj = 0; nj < 4; ++nj)
          acc[mi][nj] = __builtin_amdgcn_mfma_f32_16x16x32_bf16(
              Areg[mi][kk], Breg[nj], acc[mi][nj], 0, 0, 0);
    }

    // ---- epilogue: per-column plain sum of exp over this wave's 64 rows ----
    #pragma unroll
    for (int nj = 0; nj < 4; ++nj) {
      float sm[4];
      #pragma unroll
      for (int mi = 0; mi < 4; ++mi) {
        float e0 = exp2f(fmaf(acc[mi][nj][0], LOG2E, browl[mi * 4 + 0]));
        float e1 = exp2f(fmaf(acc[mi][nj][1], LOG2E, browl[mi * 4 + 1]));
        float e2 = exp2f(fmaf(acc[mi][nj][2], LOG2E, browl[mi * 4 + 2]));
        float e3 = exp2f(fmaf(acc[mi][nj][3], LOG2E, browl[mi * 4 + 3]));
        sm[mi] = (e0 + e1) + (e2 + e3);
      }
      float s = (sm[0] + sm[1]) + (sm[2] + sm[3]);
      // lanes {c, c+16, c+32, c+48} hold the same column -> fold lg groups
      s += __shfl_xor(s, 16);
      s += __shfl_xor(s, 32);
      if (lane < 16)
        atomicAdd(&S[colbase + wn * 64 + nj * 16 + lane], s);
    }
  }
}

// ---------------------------------------------------------------------------
// Reduce: per batch col, read S[b]; exact fp32 target logit via 4-thread dot.
// ---------------------------------------------------------------------------
__global__ __launch_bounds__(256)
void reduce_kernel(const float* __restrict__ S,
                   const float* __restrict__ X, const float* __restrict__ E,
                   const float* __restrict__ bias, const int* __restrict__ y,
                   float* __restrict__ loss)
{
  int t  = threadIdx.x;
  int tx = t >> 2;            // 0..63 -> column
  int ty = t & 3;             // 0..3  -> dot stripe
  int b  = blockIdx.x * 64 + tx;

  int yb = y[b];
  const f32x4* xr = (const f32x4*)(X + (size_t)b  * D_K);
  const f32x4* er = (const f32x4*)(E + (size_t)yb * D_K);
  float dot = 0.f;
  #pragma unroll
  for (int j = 0; j < 8; ++j) {
    f32x4 a = xr[ty * 8 + j], e = er[ty * 8 + j];
    dot += a[0]*e[0] + a[1]*e[1] + a[2]*e[2] + a[3]*e[3];
  }
  dot += __shfl_xor(dot, 1);
  dot += __shfl_xor(dot, 2);

  if (ty == 0)
    loss[b] = 0.6931471805599453f * log2f(S[b]) - (dot + bias[yb]);
}

__global__ __launch_bounds__(256)
void final_kernel(const float* __restrict__ loss, float* __restrict__ out)
{
  __shared__ float wsum[4];
  int t = threadIdx.x;
  float s = 0.f;
  for (int j = t; j < B_BATCH; j += 256) s += loss[j];
  #pragma unroll
  for (int sh = 1; sh <= 32; sh <<= 1) s += __shfl_xor(s, sh);
  if ((t & 63) == 0) wsum[t >> 6] = s;
  __syncthreads();
  if (t == 0) out[0] = (wsum[0] + wsum[1] + wsum[2] + wsum[3]) / (float)B_BATCH;
}

extern "C" void kernel_launch(void* const* d_in, const int* in_sizes, int n_in,
                              void* d_out, int out_size, void* d_ws, size_t ws_size,
                              hipStream_t stream)
{
  (void)in_sizes; (void)n_in; (void)out_size; (void)ws_size;
  const float* X    = (const float*)d_in[0];   // entity_embeddings [2048,128]
  const float* E    = (const float*)d_in[1];   // entity_embs [100000,128]
  const float* bias = (const float*)d_in[2];   // rec_entity_bias [100000]
  const int*   y    = (const int*)d_in[3];     // labels [2048]
  float* out = (float*)d_out;

  // ws layout: S float[2048] | Xb bf16[2048*128] | loss float[2048]
  float*          S    = (float*)d_ws;
  unsigned short* Xb   = (unsigned short*)((char*)d_ws + B_BATCH * sizeof(float));
  float*          loss = (float*)((char*)Xb + (size_t)B_BATCH * D_K * sizeof(unsigned short));

  convert_x_kernel<<<(B_BATCH * D_K / 8) / 256, 256, 0, stream>>>(X, Xb, S);
  fused_lse_kernel<<<NCHUNK * NBH, 256, 0, stream>>>(Xb, E, bias, S);
  reduce_kernel<<<B_BATCH / 64, 256, 0, stream>>>(S, X, E, bias, y, loss);
  final_kernel<<<1, 256, 0, stream>>>(loss, out);
}

// Round 4
// 196.904 us; speedup vs baseline: 1.7530x; 1.5631x over previous
//
#include <hip/hip_runtime.h>
#include <stdint.h>

// Problem constants
#define B_BATCH 2048     // batch rows (softmax columns here)
#define D_K     128      // embedding dim = GEMM K
#define N_ENT   100000   // entities (LSE reduction axis)
#define TROWS   128      // E rows per LDS tile
#define NTILES  ((N_ENT + TROWS - 1) / TROWS)   // 782
#define N_PAD   (NTILES * TROWS)                // 100096
#define ESPLIT  96       // entity stripes
#define NCG     8        // col groups of 256 cols (4 waves x 64)
#define LOG2E_F 1.4426950408889634f

typedef __attribute__((ext_vector_type(8))) __bf16 bf16x8;
typedef __attribute__((ext_vector_type(8))) short  short8;
typedef __attribute__((ext_vector_type(4))) float  f32x4;

__device__ __forceinline__ short f2bf(float x) {
  // RNE fp32 -> bf16
  unsigned int u = __float_as_uint(x);
  unsigned int r = (u + 0x7fffu + ((u >> 16) & 1u)) >> 16;
  return (short)r;
}

__device__ __forceinline__ short8 pack8(f32x4 a, f32x4 b) {
  short8 v;
  v[0] = f2bf(a[0]); v[1] = f2bf(a[1]); v[2] = f2bf(a[2]); v[3] = f2bf(a[3]);
  v[4] = f2bf(b[0]); v[5] = f2bf(b[1]); v[6] = f2bf(b[2]); v[7] = f2bf(b[3]);
  return v;
}

// ---------------------------------------------------------------------------
// Prep (one pass, 100096 threads): Xb = bf16(X); biasL = bias*log2e with
// -1e30 padding for rows >= N_ENT (tail tile -> exp2 = 0); S = 0.
// ---------------------------------------------------------------------------
__global__ __launch_bounds__(256)
void prep_kernel(const float* __restrict__ X, const float* __restrict__ bias,
                 unsigned short* __restrict__ Xb, float* __restrict__ biasL,
                 float* __restrict__ S)
{
  int tid = blockIdx.x * 256 + threadIdx.x;      // 0 .. 100095
  if (tid < B_BATCH * D_K / 8) {
    int i = tid * 8;
    f32x4 f0 = *(const f32x4*)(X + i);
    f32x4 f1 = *(const f32x4*)(X + i + 4);
    *(short8*)(Xb + i) = pack8(f0, f1);
  }
  biasL[tid] = (tid < N_ENT) ? bias[tid] * LOG2E_F : -1e30f;
  if (tid < B_BATCH) S[tid] = 0.f;
}

// ---------------------------------------------------------------------------
// Main kernel. Grid = ESPLIT x NCG = 768 blocks (3/CU), 4 waves/block.
//  - Wave holds 64 batch cols RESIDENT in regs (Breg: 64 VGPR, loaded once).
//  - Streams its entity stripe in 128-row tiles through a 32KB XOR-swizzled
//    bf16 LDS tile (reg-staged: global fp32 -> pack -> ds_write_b128).
//  - Per 16-row chunk: 4 ds_read_b128 (A), 16 MFMA, 16 exp2 into register
//    running sums rs[4]. No shuffles/atomics in the loop; 4 atomics at end.
//  - Register budget ~140 (B 64 + A 16 + acc 16 + bl 4 + rs 4 + addressing)
//    so NO spilling at __launch_bounds__(256,3) (cap 170). Round-3 post-mortem:
//    VGPR_Count=96 vs ~170 live => A-fragments spilled every tile.
// ---------------------------------------------------------------------------
__global__ __launch_bounds__(256, 3)
void fused_kernel(const unsigned short* __restrict__ Xb,  // [2048][128] bf16
                  const float* __restrict__ E,            // [100000][128] fp32
                  const float* __restrict__ biasL,        // [100096] bias*log2e
                  float* __restrict__ S)                  // [2048] atomic sums
{
  __shared__ __align__(16) unsigned short tile[TROWS * D_K];  // 32 KB

  const int stripe = blockIdx.x >> 3;   // 0..95  entity stripe
  const int cg     = blockIdx.x & 7;    // col group
  const int t    = threadIdx.x;
  const int lane = t & 63;
  const int w    = t >> 6;
  const int lg   = lane >> 4;           // 0..3
  const int l15  = lane & 15;
  const int col0 = cg * 256 + w * 64;   // wave's first batch col

  // ---- resident B fragments: cols col0 + nj*16 + l15, k = kk*32 + lg*8 ----
  bf16x8 Breg[4][4];
  #pragma unroll
  for (int nj = 0; nj < 4; ++nj)
    #pragma unroll
    for (int kk = 0; kk < 4; ++kk)
      Breg[nj][kk] = __builtin_bit_cast(bf16x8,
          *(const short8*)(Xb + (size_t)(col0 + nj * 16 + l15) * D_K
                              + kk * 32 + lg * 8));

  float rs[4] = {0.f, 0.f, 0.f, 0.f};   // running sum-of-exp per nj block

  // stage mapping: wave w stages rows [w*32, w*32+32); iter i covers rows
  // w*32 + i*4 + lg, elems l15*8 .. +7 (coalesced 2KB per load pair)
  const int srow = w * 32 + lg;

  for (int g = stripe; g < NTILES; g += ESPLIT) {
    __syncthreads();                    // previous tile's readers done
    #pragma unroll
    for (int i = 0; i < 8; ++i) {
      int rl = srow + i * 4;            // row in tile
      int gr = g * TROWS + rl;          // global E row
      f32x4 f0 = {0.f,0.f,0.f,0.f}, f1 = {0.f,0.f,0.f,0.f};
      if (gr < N_ENT) {
        const float* src = E + (size_t)gr * D_K + l15 * 8;
        f0 = *(const f32x4*)src;
        f1 = *(const f32x4*)(src + 4);
      }
      // XOR swizzle on 8-elem granules: granule ^ (row&7)  (G4 / m201 pattern)
      int off = rl * D_K + ((l15 * 8) ^ ((rl & 7) << 3));
      *(short8*)&tile[off] = pack8(f0, f1);
    }
    __syncthreads();                    // tile visible

    #pragma unroll 1
    for (int c = 0; c < 8; ++c) {
      f32x4 bl = *(const f32x4*)(biasL + g * TROWS + c * 16 + lg * 4);
      const int r = c * 16 + l15;       // A-frag row; (r&7) == (l15&7)
      bf16x8 A[4];
      #pragma unroll
      for (int kk = 0; kk < 4; ++kk) {
        int off = r * D_K + (((kk * 32) + lg * 8) ^ ((l15 & 7) << 3));
        A[kk] = __builtin_bit_cast(bf16x8, *(const short8*)&tile[off]);
      }
      f32x4 acc[4];
      #pragma unroll
      for (int nj = 0; nj < 4; ++nj) acc[nj] = (f32x4){0.f, 0.f, 0.f, 0.f};
      #pragma unroll
      for (int kk = 0; kk < 4; ++kk)
        #pragma unroll
        for (int nj = 0; nj < 4; ++nj)
          acc[nj] = __builtin_amdgcn_mfma_f32_16x16x32_bf16(
              A[kk], Breg[nj][kk], acc[nj], 0, 0, 0);
      // D layout: col = lane&15, row = c*16 + lg*4 + ri  [m89/m91]
      #pragma unroll
      for (int nj = 0; nj < 4; ++nj) {
        float e0 = exp2f(fmaf(acc[nj][0], LOG2E_F, bl[0]));
        float e1 = exp2f(fmaf(acc[nj][1], LOG2E_F, bl[1]));
        float e2 = exp2f(fmaf(acc[nj][2], LOG2E_F, bl[2]));
        float e3 = exp2f(fmaf(acc[nj][3], LOG2E_F, bl[3]));
        rs[nj] += (e0 + e1) + (e2 + e3);
      }
    }
  }

  // ---- finish: fold the 4 lg groups, one atomic per column ----
  #pragma unroll
  for (int nj = 0; nj < 4; ++nj) {
    float s = rs[nj];
    s += __shfl_xor(s, 16);
    s += __shfl_xor(s, 32);
    if (lane < 16) atomicAdd(&S[col0 + nj * 16 + lane], s);
  }
}

// ---------------------------------------------------------------------------
// Reduce: per batch col, read S[b]; exact fp32 target logit via 4-thread dot.
// ---------------------------------------------------------------------------
__global__ __launch_bounds__(256)
void reduce_kernel(const float* __restrict__ S,
                   const float* __restrict__ X, const float* __restrict__ E,
                   const float* __restrict__ bias, const int* __restrict__ y,
                   float* __restrict__ loss)
{
  int t  = threadIdx.x;
  int tx = t >> 2;            // 0..63 -> column
  int ty = t & 3;             // 0..3  -> dot stripe
  int b  = blockIdx.x * 64 + tx;

  int yb = y[b];
  const f32x4* xr = (const f32x4*)(X + (size_t)b  * D_K);
  const f32x4* er = (const f32x4*)(E + (size_t)yb * D_K);
  float dot = 0.f;
  #pragma unroll
  for (int j = 0; j < 8; ++j) {
    f32x4 a = xr[ty * 8 + j], e = er[ty * 8 + j];
    dot += a[0]*e[0] + a[1]*e[1] + a[2]*e[2] + a[3]*e[3];
  }
  dot += __shfl_xor(dot, 1);
  dot += __shfl_xor(dot, 2);

  if (ty == 0)
    loss[b] = 0.6931471805599453f * log2f(S[b]) - (dot + bias[yb]);
}

__global__ __launch_bounds__(256)
void final_kernel(const float* __restrict__ loss, float* __restrict__ out)
{
  __shared__ float wsum[4];
  int t = threadIdx.x;
  float s = 0.f;
  for (int j = t; j < B_BATCH; j += 256) s += loss[j];
  #pragma unroll
  for (int sh = 1; sh <= 32; sh <<= 1) s += __shfl_xor(s, sh);
  if ((t & 63) == 0) wsum[t >> 6] = s;
  __syncthreads();
  if (t == 0) out[0] = (wsum[0] + wsum[1] + wsum[2] + wsum[3]) / (float)B_BATCH;
}

extern "C" void kernel_launch(void* const* d_in, const int* in_sizes, int n_in,
                              void* d_out, int out_size, void* d_ws, size_t ws_size,
                              hipStream_t stream)
{
  (void)in_sizes; (void)n_in; (void)out_size; (void)ws_size;
  const float* X    = (const float*)d_in[0];   // entity_embeddings [2048,128]
  const float* E    = (const float*)d_in[1];   // entity_embs [100000,128]
  const float* bias = (const float*)d_in[2];   // rec_entity_bias [100000]
  const int*   y    = (const int*)d_in[3];     // labels [2048]
  float* out = (float*)d_out;

  // ws layout: S f32[2048] | Xb bf16[2048*128] | biasL f32[100096] | loss f32[2048]
  float*          Sacc  = (float*)d_ws;
  unsigned short* Xb    = (unsigned short*)((char*)d_ws + B_BATCH * sizeof(float));
  float*          biasL = (float*)((char*)Xb + (size_t)B_BATCH * D_K * sizeof(unsigned short));
  float*          loss  = (float*)((char*)biasL + (size_t)N_PAD * sizeof(float));

  prep_kernel<<<N_PAD / 256, 256, 0, stream>>>(X, bias, Xb, biasL, Sacc);
  fused_kernel<<<ESPLIT * NCG, 256, 0, stream>>>(Xb, E, biasL, Sacc);
  reduce_kernel<<<B_BATCH / 64, 256, 0, stream>>>(Sacc, X, E, bias, y, loss);
  final_kernel<<<1, 256, 0, stream>>>(loss, out);
}

// Round 6
// 187.548 us; speedup vs baseline: 1.8405x; 1.0499x over previous
//
#include <hip/hip_runtime.h>
#include <stdint.h>

// Problem constants
#define B_BATCH 2048     // batch rows (softmax columns here)
#define D_K     128      // embedding dim = GEMM K
#define N_ENT   100000   // entities (LSE reduction axis)
#define TROWS   128      // E rows per LDS tile
#define NTILES  ((N_ENT + TROWS - 1) / TROWS)   // 782
#define N_PAD   (NTILES * TROWS)                // 100096
#define ESPLIT  128      // entity stripes (16 per XCD)
#define NCG     8        // col groups of 256 cols (4 waves x 64)
#define LOG2E_F 1.4426950408889634f

typedef __attribute__((ext_vector_type(8))) __bf16 bf16x8;
typedef __attribute__((ext_vector_type(8))) short  short8;
typedef __attribute__((ext_vector_type(4))) float  f32x4;
typedef __attribute__((ext_vector_type(4))) unsigned int u32x4;

__device__ __forceinline__ short f2bf(float x) {
  // RNE fp32 -> bf16 (used for X only; X multiplies every logit, keep unbiased)
  unsigned int u = __float_as_uint(x);
  unsigned int r = (u + 0x7fffu + ((u >> 16) & 1u)) >> 16;
  return (short)r;
}

__device__ __forceinline__ short8 pack8(f32x4 a, f32x4 b) {
  short8 v;
  v[0] = f2bf(a[0]); v[1] = f2bf(a[1]); v[2] = f2bf(a[2]); v[3] = f2bf(a[3]);
  v[4] = f2bf(b[0]); v[5] = f2bf(b[1]); v[6] = f2bf(b[2]); v[7] = f2bf(b[3]);
  return v;
}

// Truncating fp32->bf16 pack, 1 v_perm_b32 per 2 elems (round-4 post-mortem:
// RNE pack was ~512 VALU ops/tile/thread, the largest VALU consumer).
// sel 0x07060302: dst = [src1.hi16, src0.hi16] -> (bf(lo), bf(hi)) in mem order.
__device__ __forceinline__ short8 pack8t(f32x4 a, f32x4 b) {
  u32x4 w;
  w[0] = __builtin_amdgcn_perm(__float_as_uint(a[1]), __float_as_uint(a[0]), 0x07060302u);
  w[1] = __builtin_amdgcn_perm(__float_as_uint(a[3]), __float_as_uint(a[2]), 0x07060302u);
  w[2] = __builtin_amdgcn_perm(__float_as_uint(b[1]), __float_as_uint(b[0]), 0x07060302u);
  w[3] = __builtin_amdgcn_perm(__float_as_uint(b[3]), __float_as_uint(b[2]), 0x07060302u);
  return __builtin_bit_cast(short8, w);
}

// ---------------------------------------------------------------------------
// Prep (one pass, 100096 threads): Xb = bf16(X) RNE; biasL = bias*log2e with
// -1e30 padding for rows >= N_ENT (tail tile -> exp2 = 0); S = 0.
// ---------------------------------------------------------------------------
__global__ __launch_bounds__(256)
void prep_kernel(const float* __restrict__ X, const float* __restrict__ bias,
                 unsigned short* __restrict__ Xb, float* __restrict__ biasL,
                 float* __restrict__ S)
{
  int tid = blockIdx.x * 256 + threadIdx.x;      // 0 .. 100095
  if (tid < B_BATCH * D_K / 8) {
    int i = tid * 8;
    f32x4 f0 = *(const f32x4*)(X + i);
    f32x4 f1 = *(const f32x4*)(X + i + 4);
    *(short8*)(Xb + i) = pack8(f0, f1);
  }
  biasL[tid] = (tid < N_ENT) ? bias[tid] * LOG2E_F : -1e30f;
  if (tid < B_BATCH) S[tid] = 0.f;
}

// ---------------------------------------------------------------------------
// Main kernel. Grid = ESPLIT x NCG = 1024 blocks (4/CU), 4 waves/block.
//  - XCD-aware decode: the 8 col-group blocks of one entity stripe share an
//    XCD (bid&7 = xcd, round-robin dispatch) and a 64-bid dispatch window,
//    so 7 of 8 E-tile reads hit that XCD's private L2 (round 4: FETCH=201MB
//    = 8x fp32 E re-read across XCDs).
//  - Wave holds 64 batch cols RESIDENT in regs (Breg: 64 VGPR, loaded once).
//  - Streams its entity stripe in 128-row tiles through a 32KB XOR-swizzled
//    bf16 LDS tile; staging pack = v_perm truncation (8 ops vs ~64).
//  - Per 16-row chunk: 4 ds_read_b128 (A), 16 MFMA, 16 exp2 into register
//    running sums rs[4]. No shuffles/atomics in loop; 4 atomics at end.
// ---------------------------------------------------------------------------
__global__ __launch_bounds__(256, 4)
void fused_kernel(const unsigned short* __restrict__ Xb,  // [2048][128] bf16
                  const float* __restrict__ E,            // [100000][128] fp32
                  const float* __restrict__ biasL,        // [100096] bias*log2e
                  float* __restrict__ S)                  // [2048] atomic sums
{
  __shared__ __align__(16) unsigned short tile[TROWS * D_K];  // 32 KB

  const int bid    = blockIdx.x;
  const int xcd    = bid & 7;
  const int stripe = xcd * 16 + (bid >> 6);   // 0..127
  const int cg     = (bid >> 3) & 7;          // col group
  const int t    = threadIdx.x;
  const int lane = t & 63;
  const int w    = t >> 6;
  const int lg   = lane >> 4;           // 0..3
  const int l15  = lane & 15;
  const int col0 = cg * 256 + w * 64;   // wave's first batch col

  // ---- resident B fragments: cols col0 + nj*16 + l15, k = kk*32 + lg*8 ----
  bf16x8 Breg[4][4];
  #pragma unroll
  for (int nj = 0; nj < 4; ++nj)
    #pragma unroll
    for (int kk = 0; kk < 4; ++kk)
      Breg[nj][kk] = __builtin_bit_cast(bf16x8,
          *(const short8*)(Xb + (size_t)(col0 + nj * 16 + l15) * D_K
                              + kk * 32 + lg * 8));

  float rs[4] = {0.f, 0.f, 0.f, 0.f};   // running sum-of-exp per nj block

  // stage mapping: wave w stages rows [w*32, w*32+32); iter i covers rows
  // w*32 + i*4 + lg, elems l15*8 .. +7 (coalesced 2KB per load pair)
  const int srow = w * 32 + lg;

  for (int g = stripe; g < NTILES; g += ESPLIT) {
    __syncthreads();                    // previous tile's readers done
    #pragma unroll
    for (int i = 0; i < 8; ++i) {
      int rl = srow + i * 4;            // row in tile
      int gr = g * TROWS + rl;          // global E row
      f32x4 f0 = {0.f,0.f,0.f,0.f}, f1 = {0.f,0.f,0.f,0.f};
      if (gr < N_ENT) {
        const float* src = E + (size_t)gr * D_K + l15 * 8;
        f0 = *(const f32x4*)src;
        f1 = *(const f32x4*)(src + 4);
      }
      // XOR swizzle on 8-elem granules: granule ^ (row&7)  (G4 / m201 pattern)
      int off = rl * D_K + ((l15 * 8) ^ ((rl & 7) << 3));
      *(short8*)&tile[off] = pack8t(f0, f1);
    }
    __syncthreads();                    // tile visible

    #pragma unroll 1
    for (int c = 0; c < 8; ++c) {
      f32x4 bl = *(const f32x4*)(biasL + g * TROWS + c * 16 + lg * 4);
      const int r = c * 16 + l15;       // A-frag row; (r&7) == (l15&7)
      bf16x8 A[4];
      #pragma unroll
      for (int kk = 0; kk < 4; ++kk) {
        int off = r * D_K + (((kk * 32) + lg * 8) ^ ((l15 & 7) << 3));
        A[kk] = __builtin_bit_cast(bf16x8, *(const short8*)&tile[off]);
      }
      f32x4 acc[4];
      #pragma unroll
      for (int nj = 0; nj < 4; ++nj) acc[nj] = (f32x4){0.f, 0.f, 0.f, 0.f};
      #pragma unroll
      for (int kk = 0; kk < 4; ++kk)
        #pragma unroll
        for (int nj = 0; nj < 4; ++nj)
          acc[nj] = __builtin_amdgcn_mfma_f32_16x16x32_bf16(
              A[kk], Breg[nj][kk], acc[nj], 0, 0, 0);
      // D layout: col = lane&15, row = c*16 + lg*4 + ri  [m89/m91]
      #pragma unroll
      for (int nj = 0; nj < 4; ++nj) {
        float e0 = exp2f(fmaf(acc[nj][0], LOG2E_F, bl[0]));
        float e1 = exp2f(fmaf(acc[nj][1], LOG2E_F, bl[1]));
        float e2 = exp2f(fmaf(acc[nj][2], LOG2E_F, bl[2]));
        float e3 = exp2f(fmaf(acc[nj][3], LOG2E_F, bl[3]));
        rs[nj] += (e0 + e1) + (e2 + e3);
      }
    }
  }

  // ---- finish: fold the 4 lg groups, one atomic per column ----
  #pragma unroll
  for (int nj = 0; nj < 4; ++nj) {
    float s = rs[nj];
    s += __shfl_xor(s, 16);
    s += __shfl_xor(s, 32);
    if (lane < 16) atomicAdd(&S[col0 + nj * 16 + lane], s);
  }
}

// ---------------------------------------------------------------------------
// Reduce: per batch col, read S[b]; exact fp32 target logit via 4-thread dot.
// ---------------------------------------------------------------------------
__global__ __launch_bounds__(256)
void reduce_kernel(const float* __restrict__ S,
                   const float* __restrict__ X, const float* __restrict__ E,
                   const float* __restrict__ bias, const int* __restrict__ y,
                   float* __restrict__ loss)
{
  int t  = threadIdx.x;
  int tx = t >> 2;            // 0..63 -> column
  int ty = t & 3;             // 0..3  -> dot stripe
  int b  = blockIdx.x * 64 + tx;

  int yb = y[b];
  const f32x4* xr = (const f32x4*)(X + (size_t)b  * D_K);
  const f32x4* er = (const f32x4*)(E + (size_t)yb * D_K);
  float dot = 0.f;
  #pragma unroll
  for (int j = 0; j < 8; ++j) {
    f32x4 a = xr[ty * 8 + j], e = er[ty * 8 + j];
    dot += a[0]*e[0] + a[1]*e[1] + a[2]*e[2] + a[3]*e[3];
  }
  dot += __shfl_xor(dot, 1);
  dot += __shfl_xor(dot, 2);

  if (ty == 0)
    loss[b] = 0.6931471805599453f * log2f(S[b]) - (dot + bias[yb]);
}

__global__ __launch_bounds__(256)
void final_kernel(const float* __restrict__ loss, float* __restrict__ out)
{
  __shared__ float wsum[4];
  int t = threadIdx.x;
  float s = 0.f;
  for (int j = t; j < B_BATCH; j += 256) s += loss[j];
  #pragma unroll
  for (int sh = 1; sh <= 32; sh <<= 1) s += __shfl_xor(s, sh);
  if ((t & 63) == 0) wsum[t >> 6] = s;
  __syncthreads();
  if (t == 0) out[0] = (wsum[0] + wsum[1] + wsum[2] + wsum[3]) / (float)B_BATCH;
}

extern "C" void kernel_launch(void* const* d_in, const int* in_sizes, int n_in,
                              void* d_out, int out_size, void* d_ws, size_t ws_size,
                              hipStream_t stream)
{
  (void)in_sizes; (void)n_in; (void)out_size; (void)ws_size;
  const float* X    = (const float*)d_in[0];   // entity_embeddings [2048,128]
  const float* E    = (const float*)d_in[1];   // entity_embs [100000,128]
  const float* bias = (const float*)d_in[2];   // rec_entity_bias [100000]
  const int*   y    = (const int*)d_in[3];     // labels [2048]
  float* out = (float*)d_out;

  // ws layout: S f32[2048] | Xb bf16[2048*128] | biasL f32[100096] | loss f32[2048]
  float*          Sacc  = (float*)d_ws;
  unsigned short* Xb    = (unsigned short*)((char*)d_ws + B_BATCH * sizeof(float));
  float*          biasL = (float*)((char*)Xb + (size_t)B_BATCH * D_K * sizeof(unsigned short));
  float*          loss  = (float*)((char*)biasL + (size_t)N_PAD * sizeof(float));

  prep_kernel<<<N_PAD / 256, 256, 0, stream>>>(X, bias, Xb, biasL, Sacc);
  fused_kernel<<<ESPLIT * NCG, 256, 0, stream>>>(Xb, E, biasL, Sacc);
  reduce_kernel<<<B_BATCH / 64, 256, 0, stream>>>(Sacc, X, E, bias, y, loss);
  final_kernel<<<1, 256, 0, stream>>>(loss, out);
}